// Round 13
// baseline (3129.198 us; speedup 1.0000x reference)
//
#include <hip/hip_runtime.h>
#include <cstdint>
#include <cstddef>
#include <cmath>

#define B 4096
#define H 512
#define E 512
#define V 32000
#define NL 2
#define MAXLEN 99

typedef __attribute__((ext_vector_type(8))) short  bf16x8;
typedef __attribute__((ext_vector_type(4))) float  f32x4;
typedef __attribute__((ext_vector_type(8))) unsigned short ushort8;

__device__ __forceinline__ unsigned short f2b(float x) {
    union { float f; unsigned u; } c; c.f = x;
    unsigned r = c.u + 0x7fff + ((c.u >> 16) & 1);   // RNE to bf16
    return (unsigned short)(r >> 16);
}
__device__ __forceinline__ float b2f(unsigned short u) {
    return __uint_as_float((unsigned)u << 16);
}

#define GLOAD16(gp, lp)                                                        \
    __builtin_amdgcn_global_load_lds(                                          \
        (const __attribute__((address_space(1))) void*)(gp),                   \
        (__attribute__((address_space(3))) void*)(lp), 16, 0, 0)

// ---------------------------------------------------------------------------
// FUSED embed + attention (R12-proven)
// ---------------------------------------------------------------------------
__global__ __launch_bounds__(256) void embed_attn_kernel(
    const int* __restrict__ tok, const float* __restrict__ emb,
    const float* __restrict__ hidden0, const float* __restrict__ attn_W,
    const float* __restrict__ attn_b, const float* __restrict__ enc,
    float* __restrict__ attnw, unsigned short* __restrict__ c2b)
{
    const int b = blockIdx.x, t = threadIdx.x;
    __shared__ float qs[1024];
    __shared__ float ls[128];
    __shared__ float4 sm4[128];

    const int v = tok[b];
    const float2 e = ((const float2*)(emb + (size_t)v * E))[t];
    qs[2 * t] = e.x; qs[2 * t + 1] = e.y;
    ushort2 eb; eb.x = f2b(e.x); eb.y = f2b(e.y);
    *(ushort2*)&c2b[(size_t)b * 1024 + 2 * t] = eb;
    const float2 h = ((const float2*)(hidden0 + (size_t)b * H))[t];
    qs[512 + 2 * t] = h.x; qs[512 + 2 * t + 1] = h.y;
    __syncthreads();

    float s = -1e30f;
    if (t < MAXLEN) {
        const float4* w4 = (const float4*)(attn_W + (size_t)t * 1024);
        const float4* q4 = (const float4*)qs;
        float ax = 0.f, ay = 0.f, az = 0.f, aw = 0.f;
        #pragma unroll 8
        for (int k = 0; k < 256; ++k) {
            const float4 a = q4[k], w = w4[k];
            ax += a.x * w.x; ay += a.y * w.y; az += a.z * w.z; aw += a.w * w.w;
        }
        s = (ax + ay) + (az + aw) + attn_b[t];
    }
    if (t < 128) ls[t] = s;
    __syncthreads();

    float mx = -1e30f;
    for (int i = 0; i < 128; ++i) mx = fmaxf(mx, ls[i]);
    __syncthreads();

    float ex = 0.f;
    if (t < MAXLEN) ex = expf(s - mx);
    if (t < 128) ls[t] = ex;
    __syncthreads();

    float sum = 0.f;
    for (int i = 0; i < 128; ++i) sum += ls[i];
    const float inv = 1.0f / sum;

    if (t < MAXLEN) attnw[(size_t)b * MAXLEN + t] = ex * inv;

    const int half = t >> 7;
    const int cq   = t & 127;
    const float4* enc4 = (const float4*)(enc + (size_t)b * MAXLEN * H);
    float4 a4; a4.x = 0.f; a4.y = 0.f; a4.z = 0.f; a4.w = 0.f;
    for (int l = half; l < MAXLEN; l += 2) {
        const float wl = ls[l];
        const float4 ev = enc4[l * 128 + cq];
        a4.x += wl * ev.x; a4.y += wl * ev.y;
        a4.z += wl * ev.z; a4.w += wl * ev.w;
    }
    if (half == 0) sm4[cq] = a4;
    __syncthreads();
    if (half == 1) {
        const float4 p = sm4[cq];
        ushort4 ob;
        ob.x = f2b((p.x + a4.x) * inv);
        ob.y = f2b((p.y + a4.y) * inv);
        ob.z = f2b((p.z + a4.z) * inv);
        ob.w = f2b((p.w + a4.w) * inv);
        *(ushort4*)&c2b[(size_t)b * 1024 + 512 + 4 * cq] = ob;
    }
}

// ---------------------------------------------------------------------------
// batched fp32 -> bf16 conversion (R12-proven)
// ---------------------------------------------------------------------------
__global__ __launch_bounds__(256) void batch_f2b_kernel(
    const float* __restrict__ s0, unsigned short* __restrict__ d0, int e0,
    const float* __restrict__ s1, unsigned short* __restrict__ d1, int e1,
    const float* __restrict__ s2, unsigned short* __restrict__ d2, int e2,
    const float* __restrict__ s3, unsigned short* __restrict__ d3, int e3,
    const float* __restrict__ s4, unsigned short* __restrict__ d4)
{
    int blk = blockIdx.x;
    const float* s; unsigned short* d;
    if      (blk < e0) { s = s0; d = d0; }
    else if (blk < e1) { s = s1; d = d1; blk -= e0; }
    else if (blk < e2) { s = s2; d = d2; blk -= e1; }
    else if (blk < e3) { s = s3; d = d3; blk -= e2; }
    else               { s = s4; d = d4; blk -= e3; }
    const size_t i = ((size_t)blk * 256 + threadIdx.x) * 8;
    const float4 a = *(const float4*)(s + i);
    const float4 b = *(const float4*)(s + i + 4);
    ushort8 o;
    o[0] = f2b(a.x); o[1] = f2b(a.y); o[2] = f2b(a.z); o[3] = f2b(a.w);
    o[4] = f2b(b.x); o[5] = f2b(b.y); o[6] = f2b(b.z); o[7] = f2b(b.w);
    *(ushort8*)(d + i) = o;
}

// ---------------------------------------------------------------------------
// bf16 MFMA NT GEMM core (m97-class, 128² tile) — used for combine + GRU duals
// ---------------------------------------------------------------------------
template<int RELU, int OUTBF>
__device__ __forceinline__ void gemm_core(
    const unsigned short* __restrict__ A, const unsigned short* __restrict__ Wb,
    const float* __restrict__ bias, void* __restrict__ Cv,
    int M, int N, int K, int ldc, int colOff, int bm, int bn)
{
    __shared__ __align__(16) unsigned short As[2][4096];
    __shared__ __align__(16) unsigned short Bs[2][4096];

    const int tid  = threadIdx.x;
    const int lane = tid & 63;
    const int wid  = tid >> 6;
    const int wr   = (wid >> 1) * 64;
    const int wc   = (wid & 1) * 64;
    const int fr   = lane & 15;
    const int fk   = (lane >> 4) * 8;

    f32x4 acc[4][4];
    #pragma unroll
    for (int m = 0; m < 4; ++m)
        #pragma unroll
        for (int n = 0; n < 4; ++n) acc[m][n] = (f32x4)0.f;

    const int srow = tid >> 2;
    const int sk   = (tid & 3) * 8;

    const unsigned short* ga = A  + (size_t)(bm + srow) * K + sk;
    const unsigned short* gb = Wb + (size_t)(bn + srow) * K + sk;

    {
        GLOAD16(ga,                    &As[0][tid * 8]);
        GLOAD16(ga + (size_t)64 * K,   &As[0][2048 + tid * 8]);
        GLOAD16(gb,                    &Bs[0][tid * 8]);
        GLOAD16(gb + (size_t)64 * K,   &Bs[0][2048 + tid * 8]);
    }

    int buf = 0;
    for (int k0 = 0; k0 < K; k0 += 32) {
        __syncthreads();

        if (k0 + 32 < K) {
            const int nb = buf ^ 1;
            GLOAD16(ga + k0 + 32,                  &As[nb][tid * 8]);
            GLOAD16(ga + k0 + 32 + (size_t)64 * K, &As[nb][2048 + tid * 8]);
            GLOAD16(gb + k0 + 32,                  &Bs[nb][tid * 8]);
            GLOAD16(gb + k0 + 32 + (size_t)64 * K, &Bs[nb][2048 + tid * 8]);
        }

        bf16x8 af[4], bf_[4];
        #pragma unroll
        for (int m = 0; m < 4; ++m)
            af[m] = *(const bf16x8*)&As[buf][(wr + m * 16 + fr) * 32 + fk];
        #pragma unroll
        for (int n = 0; n < 4; ++n)
            bf_[n] = *(const bf16x8*)&Bs[buf][(wc + n * 16 + fr) * 32 + fk];

        #pragma unroll
        for (int m = 0; m < 4; ++m)
            #pragma unroll
            for (int n = 0; n < 4; ++n)
                acc[m][n] = __builtin_amdgcn_mfma_f32_16x16x32_bf16(
                    af[m], bf_[n], acc[m][n], 0, 0, 0);

        buf ^= 1;
    }

    float bv[4];
    #pragma unroll
    for (int n = 0; n < 4; ++n) bv[n] = bias[bn + wc + n * 16 + fr];

    if constexpr (OUTBF) {
        __syncthreads();
        unsigned short* smb = (wr == 0) ? (unsigned short*)As : (unsigned short*)Bs;
        #pragma unroll
        for (int m = 0; m < 4; ++m) {
            #pragma unroll
            for (int n = 0; n < 4; ++n) {
                #pragma unroll
                for (int r = 0; r < 4; ++r) {
                    float v = acc[m][n][r] + bv[n];
                    if (RELU) v = fmaxf(v, 0.f);
                    const int row  = m * 16 + (lane >> 4) * 4 + r;
                    const int col  = wc + n * 16 + fr;
                    const int cc   = col ^ ((row & 12) << 3);
                    smb[row * 128 + cc] = f2b(v);
                }
            }
        }
        __syncthreads();
        unsigned short* Cb = (unsigned short*)Cv;
        const int rrow = tid >> 4;
        const int cch  = (tid & 15) * 8;
        #pragma unroll
        for (int p = 0; p < 8; ++p) {
            const int row  = p * 16 + rrow;
            const int lrow = row & 63;
            unsigned short* smr = (p < 4) ? (unsigned short*)As : (unsigned short*)Bs;
            const int cc = cch ^ ((row & 12) << 3);
            const ushort8 v = *(const ushort8*)&smr[lrow * 128 + cc];
            *(ushort8*)&Cb[(size_t)(bm + row) * ldc + colOff + bn + cch] = v;
        }
    } else {
        float* Cf = (float*)Cv;
        #pragma unroll
        for (int m = 0; m < 4; ++m) {
            #pragma unroll
            for (int n = 0; n < 4; ++n) {
                const int col = bn + wc + n * 16 + fr;
                const int row = bm + wr + m * 16 + (lane >> 4) * 4;
                #pragma unroll
                for (int r = 0; r < 4; ++r) {
                    float v = acc[m][n][r] + bv[n];
                    if (RELU) v = fmaxf(v, 0.f);
                    Cf[(size_t)(row + r) * ldc + colOff + col] = v;
                }
            }
        }
    }
}

template<int RELU, int OUTBF, int GSWAP>
__global__ __launch_bounds__(256) void gemm_bf16_nt(
    const unsigned short* __restrict__ A, const unsigned short* __restrict__ Wb,
    const float* __restrict__ bias, void* __restrict__ Cv,
    int M, int N, int K, int ldc, int colOff)
{
    const int bn = (GSWAP ? blockIdx.y : blockIdx.x) * 128;
    const int bm = (GSWAP ? blockIdx.x : blockIdx.y) * 128;
    gemm_core<RELU, OUTBF>(A, Wb, bias, Cv, M, N, K, ldc, colOff, bm, bn);
}

__global__ __launch_bounds__(256) void gemm_bf16_dual(
    const unsigned short* __restrict__ A0, const unsigned short* __restrict__ W0,
    const float* __restrict__ b0, void* __restrict__ C0,
    const unsigned short* __restrict__ A1, const unsigned short* __restrict__ W1,
    const float* __restrict__ b1, void* __restrict__ C1,
    int M, int N, int K, int ldc)
{
    const int bn = blockIdx.x * 128;
    const int bm = blockIdx.y * 128;
    const unsigned short* A = blockIdx.z ? A1 : A0;
    const unsigned short* W = blockIdx.z ? W1 : W0;
    const float* bias       = blockIdx.z ? b1 : b0;
    void* C                 = blockIdx.z ? C1 : C0;
    gemm_core<0, 1>(A, W, bias, C, M, N, K, ldc, 0, bm, bn);
}

// ---------------------------------------------------------------------------
// LOGITS GEMM — 256x256 tile, BK=64, 8 waves, 8-phase K-half pipeline.
// LDS (dynamic, 128KB): [buf(2)][kind(4)][16KB], kind: 0=A.k0 1=B.k0 2=A.k1 3=B.k1
// Half h (h=4t+kind) staged at phase h-7 (depth 3-4 halves in flight).
// vmcnt(6) at tile boundaries (vmcnt(0) only at the last), raw s_barrier per
// phase, plain-C ds_reads (compiler lgkmcnt), setprio around MFMA cluster.
// Output: bf16 logits to top half of fp32 row slots (ldc=2V, colOff=V).
// ---------------------------------------------------------------------------
__global__ __launch_bounds__(512, 2) void gemm_logits_8ph(
    const unsigned short* __restrict__ A, const unsigned short* __restrict__ Wb,
    const float* __restrict__ bias, float* __restrict__ Cv)
{
    extern __shared__ unsigned short AB[];          // 65536 ushorts = 128 KB
    const int tid  = threadIdx.x;
    const int lane = tid & 63;
    const int wid  = tid >> 6;                      // 0..7
    const int wr   = wid >> 2;                      // 0..1  (M)
    const int wc   = wid & 3;                       // 0..3  (N)
    const int fr   = lane & 15;
    const int fk   = (lane >> 4) * 8;
    const int bm   = blockIdx.x * 256;              // M fastest (R8-proven)
    const int bn   = blockIdx.y * 256;

    constexpr int NT = 512 / 64;                    // 8 K-tiles
    constexpr int NH = 4 * NT;                      // 32 halves

    f32x4 acc[8][4];
    #pragma unroll
    for (int m = 0; m < 8; ++m)
        #pragma unroll
        for (int n = 0; n < 4; ++n) acc[m][n] = (f32x4)0.f;

    auto STAGE = [&](int h) {
        const int th   = h >> 2, kind = h & 3;
        const unsigned short* src = (kind & 1) ? Wb : A;
        const int rbase = (kind & 1) ? bn : bm;
        const int kbase = th * 64 + (kind >> 1) * 32;
        unsigned short* dst = AB + ((size_t)(th & 1) * 4 + kind) * 8192;
        #pragma unroll
        for (int j = 0; j < 2; ++j) {
            const int c = tid + j * 512;            // 0..1023; row=c>>2, kchunk=c&3
            GLOAD16(src + (size_t)(rbase + (c >> 2)) * 512 + kbase + (c & 3) * 8,
                    &dst[c * 8]);
        }
    };

    // prologue: halves 0..6 (tile0 complete + 3 halves of tile1 in flight)
    for (int h = 0; h < 7; ++h) STAGE(h);

    bf16x8 af[8];
    for (int g = 0; g < NH; ++g) {
        const int t   = g >> 2;
        const int sub = g & 3;
        const int a   = sub >> 1;                   // k-half
        const int np  = sub & 1;                    // n-pair

        if (sub == 0) {
            if (t == NT - 1) asm volatile("s_waitcnt vmcnt(0)" ::: "memory");
            else             asm volatile("s_waitcnt vmcnt(6)" ::: "memory");
            __builtin_amdgcn_s_barrier();           // tile t fully staged, visible
        }
        if (g + 7 < NH) STAGE(g + 7);

        const unsigned short* Ah = AB + ((size_t)(t & 1) * 4 + a * 2) * 8192;
        const unsigned short* Bh = AB + ((size_t)(t & 1) * 4 + a * 2 + 1) * 8192;

        if (np == 0) {
            #pragma unroll
            for (int m = 0; m < 8; ++m)
                af[m] = *(const bf16x8*)&Ah[(wr * 128 + m * 16 + fr) * 32 + fk];
        }
        const bf16x8 bf0 = *(const bf16x8*)&Bh[(wc * 64 + np * 32 + fr) * 32 + fk];
        const bf16x8 bf1 = *(const bf16x8*)&Bh[(wc * 64 + np * 32 + 16 + fr) * 32 + fk];

        __builtin_amdgcn_s_setprio(1);
        #pragma unroll
        for (int m = 0; m < 8; ++m) {
            acc[m][np * 2 + 0] = __builtin_amdgcn_mfma_f32_16x16x32_bf16(
                af[m], bf0, acc[m][np * 2 + 0], 0, 0, 0);
            acc[m][np * 2 + 1] = __builtin_amdgcn_mfma_f32_16x16x32_bf16(
                af[m], bf1, acc[m][np * 2 + 1], 0, 0, 0);
        }
        __builtin_amdgcn_s_setprio(0);
        __builtin_amdgcn_s_barrier();               // reads of this phase done
    }

    // epilogue: per-wave private 16KB region (128 rows x 64 cols bf16);
    // all K-loop LDS reads completed before the final barrier above.
    float bv[4];
    #pragma unroll
    for (int n = 0; n < 4; ++n) bv[n] = bias[bn + wc * 64 + n * 16 + fr];

    unsigned short* reg = AB + (size_t)wid * 8192;
    #pragma unroll
    for (int m = 0; m < 8; ++m) {
        #pragma unroll
        for (int n = 0; n < 4; ++n) {
            #pragma unroll
            for (int r = 0; r < 4; ++r) {
                const int row = m * 16 + (lane >> 4) * 4 + r;   // 0..127
                const int col = n * 16 + fr;                    // 0..63
                reg[row * 64 + col] = f2b(acc[m][n][r] + bv[n]);
            }
        }
    }
    unsigned short* Cb = (unsigned short*)Cv;
    const int cch = (lane & 7) * 8;
    const int r0  = lane >> 3;
    #pragma unroll
    for (int p = 0; p < 16; ++p) {
        const int row = r0 + p * 8;                 // 0..127
        const ushort8 v = *(const ushort8*)&reg[row * 64 + cch];
        *(ushort8*)&Cb[(size_t)(bm + wr * 128 + row) * (2 * V) + V + bn + wc * 64 + cch] = v;
    }
}

// ---------------------------------------------------------------------------
// fp32 NT GEMM (fallback for logits if ws too small)
// ---------------------------------------------------------------------------
template<int RELU>
__global__ __launch_bounds__(256) void gemm_nt(
    const float* __restrict__ A, const float* __restrict__ W,
    const float* __restrict__ bias, float* __restrict__ C,
    int M, int N, int K)
{
    constexpr int BM = 128, BN = 128, BK = 32;
    __shared__ float As[BK][BM + 4];
    __shared__ float Bs[BK][BN + 4];

    const int tid = threadIdx.x;
    const int bn = blockIdx.x * BN;
    const int bm = blockIdx.y * BM;
    const int tx = tid & 15;
    const int ty = tid >> 4;

    float acc[8][8];
    #pragma unroll
    for (int i = 0; i < 8; ++i)
        #pragma unroll
        for (int j = 0; j < 8; ++j) acc[i][j] = 0.f;

    const int lkv = tid & 7;
    const int lm0 = tid >> 3;

    for (int k0 = 0; k0 < K; k0 += BK) {
        #pragma unroll
        for (int r = 0; r < 4; ++r) {
            const int m = lm0 + 32 * r;
            const float4 va = *(const float4*)(A + (size_t)(bm + m) * K + k0 + lkv * 4);
            As[lkv * 4 + 0][m] = va.x; As[lkv * 4 + 1][m] = va.y;
            As[lkv * 4 + 2][m] = va.z; As[lkv * 4 + 3][m] = va.w;
            const float4 vb = *(const float4*)(W + (size_t)(bn + m) * K + k0 + lkv * 4);
            Bs[lkv * 4 + 0][m] = vb.x; Bs[lkv * 4 + 1][m] = vb.y;
            Bs[lkv * 4 + 2][m] = vb.z; Bs[lkv * 4 + 3][m] = vb.w;
        }
        __syncthreads();

        #pragma unroll
        for (int kk = 0; kk < BK; ++kk) {
            float a[8], bb[8];
            *(float4*)&a[0]  = *(const float4*)&As[kk][ty * 8];
            *(float4*)&a[4]  = *(const float4*)&As[kk][ty * 8 + 4];
            *(float4*)&bb[0] = *(const float4*)&Bs[kk][tx * 8];
            *(float4*)&bb[4] = *(const float4*)&Bs[kk][tx * 8 + 4];
            #pragma unroll
            for (int i = 0; i < 8; ++i)
                #pragma unroll
                for (int j = 0; j < 8; ++j) acc[i][j] += a[i] * bb[j];
        }
        __syncthreads();
    }

    #pragma unroll
    for (int i = 0; i < 8; ++i) {
        const int row = bm + ty * 8 + i;
        float* crow = C + (size_t)row * N + bn + tx * 8;
        #pragma unroll
        for (int j = 0; j < 8; ++j) {
            float v = acc[i][j] + bias[bn + tx * 8 + j];
            if (RELU) v = fmaxf(v, 0.f);
            crow[j] = v;
        }
    }
}

// ---------------------------------------------------------------------------
// GRU gates (vectorized x8)
// ---------------------------------------------------------------------------
__global__ __launch_bounds__(256) void gru_gates_kernel(
    const unsigned short* __restrict__ gi, const unsigned short* __restrict__ gh,
    const float* __restrict__ h, float* __restrict__ hnew,
    unsigned short* __restrict__ hnew_b)
{
    const int idx = blockIdx.x * 256 + threadIdx.x;
    const int b  = idx >> 6;
    const int j8 = (idx & 63) * 8;
    const size_t base = (size_t)b * 1536;
    const ushort8 vir = *(const ushort8*)&gi[base + j8];
    const ushort8 viz = *(const ushort8*)&gi[base + 512 + j8];
    const ushort8 vin = *(const ushort8*)&gi[base + 1024 + j8];
    const ushort8 vhr = *(const ushort8*)&gh[base + j8];
    const ushort8 vhz = *(const ushort8*)&gh[base + 512 + j8];
    const ushort8 vhn = *(const ushort8*)&gh[base + 1024 + j8];
    const size_t hi = (size_t)b * 512 + j8;
    const float4 h0 = *(const float4*)&h[hi];
    const float4 h1 = *(const float4*)&h[hi + 4];
    const float hval[8] = {h0.x, h0.y, h0.z, h0.w, h1.x, h1.y, h1.z, h1.w};
    float hv[8];
    ushort8 ob;
    #pragma unroll
    for (int k = 0; k < 8; ++k) {
        const float r = 1.f / (1.f + expf(-(b2f(vir[k]) + b2f(vhr[k]))));
        const float z = 1.f / (1.f + expf(-(b2f(viz[k]) + b2f(vhz[k]))));
        const float n = tanhf(b2f(vin[k]) + r * b2f(vhn[k]));
        hv[k] = (1.f - z) * n + z * hval[k];
        ob[k] = f2b(hv[k]);
    }
    float4 o0, o1;
    o0.x = hv[0]; o0.y = hv[1]; o0.z = hv[2]; o0.w = hv[3];
    o1.x = hv[4]; o1.y = hv[5]; o1.z = hv[6]; o1.w = hv[7];
    *(float4*)&hnew[hi]     = o0;
    *(float4*)&hnew[hi + 4] = o1;
    *(ushort8*)&hnew_b[hi]  = ob;
}

// ---------------------------------------------------------------------------
// FULL softmax from bf16 logits (R12-proven, 512 thr)
// ---------------------------------------------------------------------------
__global__ __launch_bounds__(512) void softmax_bf16_full_kernel(float* logits)
{
    const int row = blockIdx.x, t = threadIdx.x;
    __shared__ float red[512];

    const unsigned short* src = (const unsigned short*)logits + (size_t)row * (2 * V) + V;
    ushort8 buf[8];
    #pragma unroll
    for (int k = 0; k < 8; ++k) {
        const int i = t + 512 * k;
        if (i < V / 8) buf[k] = *(const ushort8*)&src[i * 8];
    }

    float mx = -1e30f;
    #pragma unroll
    for (int k = 0; k < 8; ++k) {
        const int i = t + 512 * k;
        if (i < V / 8) {
            #pragma unroll
            for (int j = 0; j < 8; ++j) mx = fmaxf(mx, b2f(buf[k][j]));
        }
    }
    red[t] = mx; __syncthreads();
    for (int s = 256; s > 0; s >>= 1) {
        if (t < s) red[t] = fmaxf(red[t], red[t + s]);
        __syncthreads();
    }
    mx = red[0]; __syncthreads();

    float sum = 0.f;
    #pragma unroll
    for (int k = 0; k < 8; ++k) {
        const int i = t + 512 * k;
        if (i < V / 8) {
            #pragma unroll
            for (int j = 0; j < 8; ++j) sum += expf(b2f(buf[k][j]) - mx);
        }
    }
    red[t] = sum; __syncthreads();
    for (int s = 256; s > 0; s >>= 1) {
        if (t < s) red[t] += red[t + s];
        __syncthreads();
    }
    const float inv = 1.f / red[0];

    float* dst = logits + (size_t)row * V;
    #pragma unroll
    for (int k = 0; k < 8; ++k) {
        const int i = t + 512 * k;
        if (i < V / 8) {
            float4 o0, o1;
            o0.x = expf(b2f(buf[k][0]) - mx) * inv;
            o0.y = expf(b2f(buf[k][1]) - mx) * inv;
            o0.z = expf(b2f(buf[k][2]) - mx) * inv;
            o0.w = expf(b2f(buf[k][3]) - mx) * inv;
            o1.x = expf(b2f(buf[k][4]) - mx) * inv;
            o1.y = expf(b2f(buf[k][5]) - mx) * inv;
            o1.z = expf(b2f(buf[k][6]) - mx) * inv;
            o1.w = expf(b2f(buf[k][7]) - mx) * inv;
            *(float4*)&dst[i * 8]     = o0;
            *(float4*)&dst[i * 8 + 4] = o1;
        }
    }
}

// ---------------------------------------------------------------------------
// in-place row softmax (fallback)
// ---------------------------------------------------------------------------
__global__ __launch_bounds__(256) void softmax_rows_kernel(float* __restrict__ logits, int N)
{
    const int b = blockIdx.x, t = threadIdx.x;
    __shared__ float red[256];
    float* row = logits + (size_t)b * N;

    float mx = -1e30f;
    for (int i = t; i < N; i += 256) mx = fmaxf(mx, row[i]);
    red[t] = mx; __syncthreads();
    for (int s = 128; s > 0; s >>= 1) { if (t < s) red[t] = fmaxf(red[t], red[t + s]); __syncthreads(); }
    mx = red[0]; __syncthreads();

    float sum = 0.f;
    for (int i = t; i < N; i += 256) sum += expf(row[i] - mx);
    red[t] = sum; __syncthreads();
    for (int s = 128; s > 0; s >>= 1) { if (t < s) red[t] += red[t + s]; __syncthreads(); }
    const float inv = 1.0f / red[0];
    __syncthreads();

    for (int i = t; i < N; i += 256) row[i] = expf(row[i] - mx) * inv;
}

// ---------------------------------------------------------------------------
extern "C" void kernel_launch(void* const* d_in, const int* in_sizes, int n_in,
                              void* d_out, int out_size, void* d_ws, size_t ws_size,
                              hipStream_t stream)
{
    const int*   tok    = (const int*)d_in[0];
    const float* hidden = (const float*)d_in[1];
    const float* enc    = (const float*)d_in[2];
    const float* emb    = (const float*)d_in[3];
    const float* attn_W = (const float*)d_in[4];
    const float* attn_b = (const float*)d_in[5];
    const float* comb_W = (const float*)d_in[6];
    const float* comb_b = (const float*)d_in[7];
    const float* W_ih   = (const float*)d_in[8];
    const float* W_hh   = (const float*)d_in[9];
    const float* b_ih   = (const float*)d_in[10];
    const float* b_hh   = (const float*)d_in[11];
    const float* out_W  = (const float*)d_in[12];
    const float* out_b  = (const float*)d_in[13];

    float* out   = (float*)d_out;
    float* pred  = out;                             // B*V
    float* hid_o = out + (size_t)B * V;             // NL*B*H
    float* attnw = hid_o + (size_t)NL * B * H;      // B*MAXLEN

    unsigned short* c2b    = (unsigned short*)pred;         // B*1024
    unsigned short* xb     = c2b  + (size_t)B * 1024;       // B*512
    unsigned short* h01b   = xb   + (size_t)B * 512;        // NL*B*512
    unsigned short* hn0b   = h01b + (size_t)NL * B * 512;   // B*512
    unsigned short* gi_b   = hn0b + (size_t)B * 512;        // B*1536
    unsigned short* gh_b   = gi_b + (size_t)B * 1536;       // B*1536
    unsigned short* Wihb   = gh_b + (size_t)B * 1536;       // 2*1536*512
    unsigned short* Whhb   = Wihb + (size_t)NL * 1536 * 512;
    unsigned short* combWb = Whhb + (size_t)NL * 1536 * 512; // 512*1024
    unsigned short* hn1b_fallback = combWb + (size_t)512 * 1024;

    const size_t outWb_e = (size_t)V * H;
    const size_t hn1b_e  = (size_t)B * H;
    const size_t bf_bytes = (outWb_e + hn1b_e) * sizeof(unsigned short);
    const bool lvl1 = ws_size >= bf_bytes;

    unsigned short* outWb = (unsigned short*)d_ws;
    unsigned short* hn1b  = lvl1 ? outWb + outWb_e : hn1b_fallback;

    unsigned short* h0b = h01b;
    unsigned short* h1b = h01b + (size_t)B * 512;

    // allow 128KB dynamic LDS for the 8-phase logits kernel (deterministic)
    (void)hipFuncSetAttribute((const void*)gemm_logits_8ph,
                              hipFuncAttributeMaxDynamicSharedMemorySize, 131072);

    // 1. fused embed + attention
    embed_attn_kernel<<<B, 256, 0, stream>>>(
        tok, emb, hidden, attn_W, attn_b, enc, attnw, c2b);

    // 2. batched conversions
    {
        const int e0 = 256, e1 = e0 + 768, e2 = e1 + 768, e3 = e2 + 2048;
        const int nblk = lvl1 ? e3 + 8000 : e3;
        batch_f2b_kernel<<<nblk, 256, 0, stream>>>(
            comb_W, combWb, e0,
            W_ih,   Wihb,   e1,
            W_hh,   Whhb,   e2,
            hidden, h01b,   e3,
            out_W,  outWb);
    }

    // 3. combine
    gemm_bf16_nt<1, 1, 0><<<dim3(512 / 128, B / 128), 256, 0, stream>>>(
        c2b, combWb, comb_b, xb, B, 512, 1024, 512, 0);

    // 4. GRU layer 0
    gemm_bf16_dual<<<dim3(1536 / 128, B / 128, 2), 256, 0, stream>>>(
        xb,  Wihb, b_ih, gi_b,
        h0b, Whhb, b_hh, gh_b, B, 1536, 512, 1536);
    gru_gates_kernel<<<(B * H / 8) / 256, 256, 0, stream>>>(
        gi_b, gh_b, hidden, hid_o, hn0b);

    // 5. GRU layer 1
    gemm_bf16_dual<<<dim3(1536 / 128, B / 128, 2), 256, 0, stream>>>(
        hn0b, Wihb + (size_t)1536 * 512, b_ih + 1536, gi_b,
        h1b,  Whhb + (size_t)1536 * 512, b_hh + 1536, gh_b, B, 1536, 512, 1536);
    gru_gates_kernel<<<(B * H / 8) / 256, 256, 0, stream>>>(
        gi_b, gh_b, hidden + (size_t)B * H, hid_o + (size_t)B * H, hn1b);

    // 6. logits (8-phase 256² kernel) + softmax
    if (lvl1) {
        gemm_logits_8ph<<<dim3(B / 256, V / 256), 512, 131072, stream>>>(
            hn1b, outWb, out_b, pred);
        softmax_bf16_full_kernel<<<B, 512, 0, stream>>>(pred);
    } else {
        gemm_nt<0><<<dim3(V / 128, B / 128), 256, 0, stream>>>(
            hid_o + (size_t)B * H, out_W, out_b, pred, B, V, 512);
        softmax_rows_kernel<<<B, 256, 0, stream>>>(pred, V);
    }
}

// Round 14
// 773.773 us; speedup vs baseline: 4.0441x; 4.0441x over previous
//
#include <hip/hip_runtime.h>
#include <cstdint>
#include <cstddef>
#include <cmath>

#define B 4096
#define H 512
#define E 512
#define V 32000
#define NL 2
#define MAXLEN 99

typedef __attribute__((ext_vector_type(8))) short  bf16x8;
typedef __attribute__((ext_vector_type(4))) float  f32x4;
typedef __attribute__((ext_vector_type(8))) unsigned short ushort8;

__device__ __forceinline__ unsigned short f2b(float x) {
    union { float f; unsigned u; } c; c.f = x;
    unsigned r = c.u + 0x7fff + ((c.u >> 16) & 1);   // RNE to bf16
    return (unsigned short)(r >> 16);
}
__device__ __forceinline__ float b2f(unsigned short u) {
    return __uint_as_float((unsigned)u << 16);
}

#define GLOAD16(gp, lp)                                                        \
    __builtin_amdgcn_global_load_lds(                                          \
        (const __attribute__((address_space(1))) void*)(gp),                   \
        (__attribute__((address_space(3))) void*)(lp), 16, 0, 0)

// ---------------------------------------------------------------------------
// FUSED embed + attention (R12-proven)
// ---------------------------------------------------------------------------
__global__ __launch_bounds__(256) void embed_attn_kernel(
    const int* __restrict__ tok, const float* __restrict__ emb,
    const float* __restrict__ hidden0, const float* __restrict__ attn_W,
    const float* __restrict__ attn_b, const float* __restrict__ enc,
    float* __restrict__ attnw, unsigned short* __restrict__ c2b)
{
    const int b = blockIdx.x, t = threadIdx.x;
    __shared__ float qs[1024];
    __shared__ float ls[128];
    __shared__ float4 sm4[128];

    const int v = tok[b];
    const float2 e = ((const float2*)(emb + (size_t)v * E))[t];
    qs[2 * t] = e.x; qs[2 * t + 1] = e.y;
    ushort2 eb; eb.x = f2b(e.x); eb.y = f2b(e.y);
    *(ushort2*)&c2b[(size_t)b * 1024 + 2 * t] = eb;
    const float2 h = ((const float2*)(hidden0 + (size_t)b * H))[t];
    qs[512 + 2 * t] = h.x; qs[512 + 2 * t + 1] = h.y;
    __syncthreads();

    float s = -1e30f;
    if (t < MAXLEN) {
        const float4* w4 = (const float4*)(attn_W + (size_t)t * 1024);
        const float4* q4 = (const float4*)qs;
        float ax = 0.f, ay = 0.f, az = 0.f, aw = 0.f;
        #pragma unroll 8
        for (int k = 0; k < 256; ++k) {
            const float4 a = q4[k], w = w4[k];
            ax += a.x * w.x; ay += a.y * w.y; az += a.z * w.z; aw += a.w * w.w;
        }
        s = (ax + ay) + (az + aw) + attn_b[t];
    }
    if (t < 128) ls[t] = s;
    __syncthreads();

    float mx = -1e30f;
    for (int i = 0; i < 128; ++i) mx = fmaxf(mx, ls[i]);
    __syncthreads();

    float ex = 0.f;
    if (t < MAXLEN) ex = expf(s - mx);
    if (t < 128) ls[t] = ex;
    __syncthreads();

    float sum = 0.f;
    for (int i = 0; i < 128; ++i) sum += ls[i];
    const float inv = 1.0f / sum;

    if (t < MAXLEN) attnw[(size_t)b * MAXLEN + t] = ex * inv;

    const int half = t >> 7;
    const int cq   = t & 127;
    const float4* enc4 = (const float4*)(enc + (size_t)b * MAXLEN * H);
    float4 a4; a4.x = 0.f; a4.y = 0.f; a4.z = 0.f; a4.w = 0.f;
    for (int l = half; l < MAXLEN; l += 2) {
        const float wl = ls[l];
        const float4 ev = enc4[l * 128 + cq];
        a4.x += wl * ev.x; a4.y += wl * ev.y;
        a4.z += wl * ev.z; a4.w += wl * ev.w;
    }
    if (half == 0) sm4[cq] = a4;
    __syncthreads();
    if (half == 1) {
        const float4 p = sm4[cq];
        ushort4 ob;
        ob.x = f2b((p.x + a4.x) * inv);
        ob.y = f2b((p.y + a4.y) * inv);
        ob.z = f2b((p.z + a4.z) * inv);
        ob.w = f2b((p.w + a4.w) * inv);
        *(ushort4*)&c2b[(size_t)b * 1024 + 512 + 4 * cq] = ob;
    }
}

// ---------------------------------------------------------------------------
// batched fp32 -> bf16 conversion (R12-proven)
// ---------------------------------------------------------------------------
__global__ __launch_bounds__(256) void batch_f2b_kernel(
    const float* __restrict__ s0, unsigned short* __restrict__ d0, int e0,
    const float* __restrict__ s1, unsigned short* __restrict__ d1, int e1,
    const float* __restrict__ s2, unsigned short* __restrict__ d2, int e2,
    const float* __restrict__ s3, unsigned short* __restrict__ d3, int e3,
    const float* __restrict__ s4, unsigned short* __restrict__ d4)
{
    int blk = blockIdx.x;
    const float* s; unsigned short* d;
    if      (blk < e0) { s = s0; d = d0; }
    else if (blk < e1) { s = s1; d = d1; blk -= e0; }
    else if (blk < e2) { s = s2; d = d2; blk -= e1; }
    else if (blk < e3) { s = s3; d = d3; blk -= e2; }
    else               { s = s4; d = d4; blk -= e3; }
    const size_t i = ((size_t)blk * 256 + threadIdx.x) * 8;
    const float4 a = *(const float4*)(s + i);
    const float4 b = *(const float4*)(s + i + 4);
    ushort8 o;
    o[0] = f2b(a.x); o[1] = f2b(a.y); o[2] = f2b(a.z); o[3] = f2b(a.w);
    o[4] = f2b(b.x); o[5] = f2b(b.y); o[6] = f2b(b.z); o[7] = f2b(b.w);
    *(ushort8*)(d + i) = o;
}

// ---------------------------------------------------------------------------
// bf16 MFMA NT GEMM core (m97-class, 128² tile) — combine + GRU duals
// ---------------------------------------------------------------------------
template<int RELU, int OUTBF>
__device__ __forceinline__ void gemm_core(
    const unsigned short* __restrict__ A, const unsigned short* __restrict__ Wb,
    const float* __restrict__ bias, void* __restrict__ Cv,
    int M, int N, int K, int ldc, int colOff, int bm, int bn)
{
    __shared__ __align__(16) unsigned short As[2][4096];
    __shared__ __align__(16) unsigned short Bs[2][4096];

    const int tid  = threadIdx.x;
    const int lane = tid & 63;
    const int wid  = tid >> 6;
    const int wr   = (wid >> 1) * 64;
    const int wc   = (wid & 1) * 64;
    const int fr   = lane & 15;
    const int fk   = (lane >> 4) * 8;

    f32x4 acc[4][4];
    #pragma unroll
    for (int m = 0; m < 4; ++m)
        #pragma unroll
        for (int n = 0; n < 4; ++n) acc[m][n] = (f32x4)0.f;

    const int srow = tid >> 2;
    const int sk   = (tid & 3) * 8;

    const unsigned short* ga = A  + (size_t)(bm + srow) * K + sk;
    const unsigned short* gb = Wb + (size_t)(bn + srow) * K + sk;

    {
        GLOAD16(ga,                    &As[0][tid * 8]);
        GLOAD16(ga + (size_t)64 * K,   &As[0][2048 + tid * 8]);
        GLOAD16(gb,                    &Bs[0][tid * 8]);
        GLOAD16(gb + (size_t)64 * K,   &Bs[0][2048 + tid * 8]);
    }

    int buf = 0;
    for (int k0 = 0; k0 < K; k0 += 32) {
        __syncthreads();

        if (k0 + 32 < K) {
            const int nb = buf ^ 1;
            GLOAD16(ga + k0 + 32,                  &As[nb][tid * 8]);
            GLOAD16(ga + k0 + 32 + (size_t)64 * K, &As[nb][2048 + tid * 8]);
            GLOAD16(gb + k0 + 32,                  &Bs[nb][tid * 8]);
            GLOAD16(gb + k0 + 32 + (size_t)64 * K, &Bs[nb][2048 + tid * 8]);
        }

        bf16x8 af[4], bf_[4];
        #pragma unroll
        for (int m = 0; m < 4; ++m)
            af[m] = *(const bf16x8*)&As[buf][(wr + m * 16 + fr) * 32 + fk];
        #pragma unroll
        for (int n = 0; n < 4; ++n)
            bf_[n] = *(const bf16x8*)&Bs[buf][(wc + n * 16 + fr) * 32 + fk];

        #pragma unroll
        for (int m = 0; m < 4; ++m)
            #pragma unroll
            for (int n = 0; n < 4; ++n)
                acc[m][n] = __builtin_amdgcn_mfma_f32_16x16x32_bf16(
                    af[m], bf_[n], acc[m][n], 0, 0, 0);

        buf ^= 1;
    }

    float bv[4];
    #pragma unroll
    for (int n = 0; n < 4; ++n) bv[n] = bias[bn + wc + n * 16 + fr];

    if constexpr (OUTBF) {
        __syncthreads();
        unsigned short* smb = (wr == 0) ? (unsigned short*)As : (unsigned short*)Bs;
        #pragma unroll
        for (int m = 0; m < 4; ++m) {
            #pragma unroll
            for (int n = 0; n < 4; ++n) {
                #pragma unroll
                for (int r = 0; r < 4; ++r) {
                    float v = acc[m][n][r] + bv[n];
                    if (RELU) v = fmaxf(v, 0.f);
                    const int row  = m * 16 + (lane >> 4) * 4 + r;
                    const int col  = wc + n * 16 + fr;
                    const int cc   = col ^ ((row & 12) << 3);
                    smb[row * 128 + cc] = f2b(v);
                }
            }
        }
        __syncthreads();
        unsigned short* Cb = (unsigned short*)Cv;
        const int rrow = tid >> 4;
        const int cch  = (tid & 15) * 8;
        #pragma unroll
        for (int p = 0; p < 8; ++p) {
            const int row  = p * 16 + rrow;
            const int lrow = row & 63;
            unsigned short* smr = (p < 4) ? (unsigned short*)As : (unsigned short*)Bs;
            const int cc = cch ^ ((row & 12) << 3);
            const ushort8 v = *(const ushort8*)&smr[lrow * 128 + cc];
            *(ushort8*)&Cb[(size_t)(bm + row) * ldc + colOff + bn + cch] = v;
        }
    } else {
        float* Cf = (float*)Cv;
        #pragma unroll
        for (int m = 0; m < 4; ++m) {
            #pragma unroll
            for (int n = 0; n < 4; ++n) {
                const int col = bn + wc + n * 16 + fr;
                const int row = bm + wr + m * 16 + (lane >> 4) * 4;
                #pragma unroll
                for (int r = 0; r < 4; ++r) {
                    float v = acc[m][n][r] + bv[n];
                    if (RELU) v = fmaxf(v, 0.f);
                    Cf[(size_t)(row + r) * ldc + colOff + col] = v;
                }
            }
        }
    }
}

template<int RELU, int OUTBF, int GSWAP>
__global__ __launch_bounds__(256) void gemm_bf16_nt(
    const unsigned short* __restrict__ A, const unsigned short* __restrict__ Wb,
    const float* __restrict__ bias, void* __restrict__ Cv,
    int M, int N, int K, int ldc, int colOff)
{
    const int bn = (GSWAP ? blockIdx.y : blockIdx.x) * 128;
    const int bm = (GSWAP ? blockIdx.x : blockIdx.y) * 128;
    gemm_core<RELU, OUTBF>(A, Wb, bias, Cv, M, N, K, ldc, colOff, bm, bn);
}

__global__ __launch_bounds__(256) void gemm_bf16_dual(
    const unsigned short* __restrict__ A0, const unsigned short* __restrict__ W0,
    const float* __restrict__ b0, void* __restrict__ C0,
    const unsigned short* __restrict__ A1, const unsigned short* __restrict__ W1,
    const float* __restrict__ b1, void* __restrict__ C1,
    int M, int N, int K, int ldc)
{
    const int bn = blockIdx.x * 128;
    const int bm = blockIdx.y * 128;
    const unsigned short* A = blockIdx.z ? A1 : A0;
    const unsigned short* W = blockIdx.z ? W1 : W0;
    const float* bias       = blockIdx.z ? b1 : b0;
    void* C                 = blockIdx.z ? C1 : C0;
    gemm_core<0, 1>(A, W, bias, C, M, N, K, ldc, 0, bm, bn);
}

// ---------------------------------------------------------------------------
// LOGITS GEMM — 256x256, BK=64, 8 waves, 8-phase K-half pipeline.
// R13's schedule verified CORRECT on HW; R13's perf bug was rule #20 (dynamic
// phase loop -> runtime-indexed acc -> scratch). Fix: FULLY UNROLLED phases,
// every acc/af index compile-time -> registers (~210 VGPR, 1 block/CU via
// 128KB LDS, 2 waves/SIMD).
// ---------------------------------------------------------------------------
__global__ __launch_bounds__(512, 2) void gemm_logits_8ph(
    const unsigned short* __restrict__ A, const unsigned short* __restrict__ Wb,
    const float* __restrict__ bias, float* __restrict__ Cv)
{
    extern __shared__ unsigned short AB[];          // 65536 ushorts = 128 KB
    const int tid  = threadIdx.x;
    const int lane = tid & 63;
    const int wid  = tid >> 6;                      // 0..7
    const int wr   = wid >> 2;                      // 0..1  (M)
    const int wc   = wid & 3;                       // 0..3  (N)
    const int fr   = lane & 15;
    const int fk   = (lane >> 4) * 8;
    const int bm   = blockIdx.x * 256;              // M fastest
    const int bn   = blockIdx.y * 256;

    constexpr int NT = 512 / 64;                    // 8 K-tiles
    constexpr int NH = 4 * NT;                      // 32 halves

    f32x4 acc[8][4];
    #pragma unroll
    for (int m = 0; m < 8; ++m)
        #pragma unroll
        for (int n = 0; n < 4; ++n) acc[m][n] = (f32x4)0.f;

    auto STAGE = [&](int h) {
        const int th   = h >> 2, kind = h & 3;
        const unsigned short* src = (kind & 1) ? Wb : A;
        const int rbase = (kind & 1) ? bn : bm;
        const int kbase = th * 64 + (kind >> 1) * 32;
        unsigned short* dst = AB + ((size_t)(th & 1) * 4 + kind) * 8192;
        #pragma unroll
        for (int j = 0; j < 2; ++j) {
            const int c = tid + j * 512;            // 0..1023; row=c>>2, kchunk=c&3
            GLOAD16(src + (size_t)(rbase + (c >> 2)) * 512 + kbase + (c & 3) * 8,
                    &dst[c * 8]);
        }
    };

    // prologue: halves 0..6 (tile0 complete + 3 halves of tile1 in flight)
    #pragma unroll
    for (int h = 0; h < 7; ++h) STAGE(h);

    bf16x8 af[8];
    #pragma unroll
    for (int t = 0; t < NT; ++t) {                  // COMPILE-TIME tiles
        #pragma unroll
        for (int sub = 0; sub < 4; ++sub) {         // COMPILE-TIME sub-phases
            const int g  = t * 4 + sub;
            const int a  = sub >> 1;                // k-half (const)
            const int np = sub & 1;                 // n-pair (const)

            if (sub == 0) {
                if (t == NT - 1) asm volatile("s_waitcnt vmcnt(0)" ::: "memory");
                else             asm volatile("s_waitcnt vmcnt(6)" ::: "memory");
                __builtin_amdgcn_s_barrier();       // tile t staged + visible
            }
            if (g + 7 < NH) STAGE(g + 7);

            const unsigned short* Ah = AB + ((size_t)(t & 1) * 4 + a * 2) * 8192;
            const unsigned short* Bh = AB + ((size_t)(t & 1) * 4 + a * 2 + 1) * 8192;

            if (np == 0) {
                #pragma unroll
                for (int m = 0; m < 8; ++m)
                    af[m] = *(const bf16x8*)&Ah[(wr * 128 + m * 16 + fr) * 32 + fk];
            }
            const bf16x8 bf0 = *(const bf16x8*)&Bh[(wc * 64 + np * 32 + fr) * 32 + fk];
            const bf16x8 bf1 = *(const bf16x8*)&Bh[(wc * 64 + np * 32 + 16 + fr) * 32 + fk];

            __builtin_amdgcn_s_setprio(1);
            #pragma unroll
            for (int m = 0; m < 8; ++m) {
                acc[m][np * 2 + 0] = __builtin_amdgcn_mfma_f32_16x16x32_bf16(
                    af[m], bf0, acc[m][np * 2 + 0], 0, 0, 0);
                acc[m][np * 2 + 1] = __builtin_amdgcn_mfma_f32_16x16x32_bf16(
                    af[m], bf1, acc[m][np * 2 + 1], 0, 0, 0);
            }
            __builtin_amdgcn_s_setprio(0);
            __builtin_amdgcn_s_barrier();           // reads of this phase done
        }
    }

    // epilogue: per-wave private 16KB LDS region -> dense ushort8 stores
    float bv[4];
    #pragma unroll
    for (int n = 0; n < 4; ++n) bv[n] = bias[bn + wc * 64 + n * 16 + fr];

    unsigned short* reg = AB + (size_t)wid * 8192;
    #pragma unroll
    for (int m = 0; m < 8; ++m) {
        #pragma unroll
        for (int n = 0; n < 4; ++n) {
            #pragma unroll
            for (int r = 0; r < 4; ++r) {
                const int row = m * 16 + (lane >> 4) * 4 + r;   // 0..127
                const int col = n * 16 + fr;                    // 0..63
                reg[row * 64 + col] = f2b(acc[m][n][r] + bv[n]);
            }
        }
    }
    unsigned short* Cb = (unsigned short*)Cv;
    const int cch = (lane & 7) * 8;
    const int r0  = lane >> 3;
    #pragma unroll
    for (int p = 0; p < 16; ++p) {
        const int row = r0 + p * 8;                 // 0..127
        const ushort8 v = *(const ushort8*)&reg[row * 64 + cch];
        *(ushort8*)&Cb[(size_t)(bm + wr * 128 + row) * (2 * V) + V + bn + wc * 64 + cch] = v;
    }
}

// ---------------------------------------------------------------------------
// fp32 NT GEMM (fallback for logits if ws too small)
// ---------------------------------------------------------------------------
template<int RELU>
__global__ __launch_bounds__(256) void gemm_nt(
    const float* __restrict__ A, const float* __restrict__ W,
    const float* __restrict__ bias, float* __restrict__ C,
    int M, int N, int K)
{
    constexpr int BM = 128, BN = 128, BK = 32;
    __shared__ float As[BK][BM + 4];
    __shared__ float Bs[BK][BN + 4];

    const int tid = threadIdx.x;
    const int bn = blockIdx.x * BN;
    const int bm = blockIdx.y * BM;
    const int tx = tid & 15;
    const int ty = tid >> 4;

    float acc[8][8];
    #pragma unroll
    for (int i = 0; i < 8; ++i)
        #pragma unroll
        for (int j = 0; j < 8; ++j) acc[i][j] = 0.f;

    const int lkv = tid & 7;
    const int lm0 = tid >> 3;

    for (int k0 = 0; k0 < K; k0 += BK) {
        #pragma unroll
        for (int r = 0; r < 4; ++r) {
            const int m = lm0 + 32 * r;
            const float4 va = *(const float4*)(A + (size_t)(bm + m) * K + k0 + lkv * 4);
            As[lkv * 4 + 0][m] = va.x; As[lkv * 4 + 1][m] = va.y;
            As[lkv * 4 + 2][m] = va.z; As[lkv * 4 + 3][m] = va.w;
            const float4 vb = *(const float4*)(W + (size_t)(bn + m) * K + k0 + lkv * 4);
            Bs[lkv * 4 + 0][m] = vb.x; Bs[lkv * 4 + 1][m] = vb.y;
            Bs[lkv * 4 + 2][m] = vb.z; Bs[lkv * 4 + 3][m] = vb.w;
        }
        __syncthreads();

        #pragma unroll
        for (int kk = 0; kk < BK; ++kk) {
            float a[8], bb[8];
            *(float4*)&a[0]  = *(const float4*)&As[kk][ty * 8];
            *(float4*)&a[4]  = *(const float4*)&As[kk][ty * 8 + 4];
            *(float4*)&bb[0] = *(const float4*)&Bs[kk][tx * 8];
            *(float4*)&bb[4] = *(const float4*)&Bs[kk][tx * 8 + 4];
            #pragma unroll
            for (int i = 0; i < 8; ++i)
                #pragma unroll
                for (int j = 0; j < 8; ++j) acc[i][j] += a[i] * bb[j];
        }
        __syncthreads();
    }

    #pragma unroll
    for (int i = 0; i < 8; ++i) {
        const int row = bm + ty * 8 + i;
        float* crow = C + (size_t)row * N + bn + tx * 8;
        #pragma unroll
        for (int j = 0; j < 8; ++j) {
            float v = acc[i][j] + bias[bn + tx * 8 + j];
            if (RELU) v = fmaxf(v, 0.f);
            crow[j] = v;
        }
    }
}

// ---------------------------------------------------------------------------
// GRU gates (vectorized x8)
// ---------------------------------------------------------------------------
__global__ __launch_bounds__(256) void gru_gates_kernel(
    const unsigned short* __restrict__ gi, const unsigned short* __restrict__ gh,
    const float* __restrict__ h, float* __restrict__ hnew,
    unsigned short* __restrict__ hnew_b)
{
    const int idx = blockIdx.x * 256 + threadIdx.x;
    const int b  = idx >> 6;
    const int j8 = (idx & 63) * 8;
    const size_t base = (size_t)b * 1536;
    const ushort8 vir = *(const ushort8*)&gi[base + j8];
    const ushort8 viz = *(const ushort8*)&gi[base + 512 + j8];
    const ushort8 vin = *(const ushort8*)&gi[base + 1024 + j8];
    const ushort8 vhr = *(const ushort8*)&gh[base + j8];
    const ushort8 vhz = *(const ushort8*)&gh[base + 512 + j8];
    const ushort8 vhn = *(const ushort8*)&gh[base + 1024 + j8];
    const size_t hi = (size_t)b * 512 + j8;
    const float4 h0 = *(const float4*)&h[hi];
    const float4 h1 = *(const float4*)&h[hi + 4];
    const float hval[8] = {h0.x, h0.y, h0.z, h0.w, h1.x, h1.y, h1.z, h1.w};
    float hv[8];
    ushort8 ob;
    #pragma unroll
    for (int k = 0; k < 8; ++k) {
        const float r = 1.f / (1.f + expf(-(b2f(vir[k]) + b2f(vhr[k]))));
        const float z = 1.f / (1.f + expf(-(b2f(viz[k]) + b2f(vhz[k]))));
        const float n = tanhf(b2f(vin[k]) + r * b2f(vhn[k]));
        hv[k] = (1.f - z) * n + z * hval[k];
        ob[k] = f2b(hv[k]);
    }
    float4 o0, o1;
    o0.x = hv[0]; o0.y = hv[1]; o0.z = hv[2]; o0.w = hv[3];
    o1.x = hv[4]; o1.y = hv[5]; o1.z = hv[6]; o1.w = hv[7];
    *(float4*)&hnew[hi]     = o0;
    *(float4*)&hnew[hi + 4] = o1;
    *(ushort8*)&hnew_b[hi]  = ob;
}

// ---------------------------------------------------------------------------
// FULL softmax from bf16 logits (R12-proven, 512 thr)
// ---------------------------------------------------------------------------
__global__ __launch_bounds__(512) void softmax_bf16_full_kernel(float* logits)
{
    const int row = blockIdx.x, t = threadIdx.x;
    __shared__ float red[512];

    const unsigned short* src = (const unsigned short*)logits + (size_t)row * (2 * V) + V;
    ushort8 buf[8];
    #pragma unroll
    for (int k = 0; k < 8; ++k) {
        const int i = t + 512 * k;
        if (i < V / 8) buf[k] = *(const ushort8*)&src[i * 8];
    }

    float mx = -1e30f;
    #pragma unroll
    for (int k = 0; k < 8; ++k) {
        const int i = t + 512 * k;
        if (i < V / 8) {
            #pragma unroll
            for (int j = 0; j < 8; ++j) mx = fmaxf(mx, b2f(buf[k][j]));
        }
    }
    red[t] = mx; __syncthreads();
    for (int s = 256; s > 0; s >>= 1) {
        if (t < s) red[t] = fmaxf(red[t], red[t + s]);
        __syncthreads();
    }
    mx = red[0]; __syncthreads();

    float sum = 0.f;
    #pragma unroll
    for (int k = 0; k < 8; ++k) {
        const int i = t + 512 * k;
        if (i < V / 8) {
            #pragma unroll
            for (int j = 0; j < 8; ++j) sum += expf(b2f(buf[k][j]) - mx);
        }
    }
    red[t] = sum; __syncthreads();
    for (int s = 256; s > 0; s >>= 1) {
        if (t < s) red[t] += red[t + s];
        __syncthreads();
    }
    const float inv = 1.f / red[0];

    float* dst = logits + (size_t)row * V;
    #pragma unroll
    for (int k = 0; k < 8; ++k) {
        const int i = t + 512 * k;
        if (i < V / 8) {
            float4 o0, o1;
            o0.x = expf(b2f(buf[k][0]) - mx) * inv;
            o0.y = expf(b2f(buf[k][1]) - mx) * inv;
            o0.z = expf(b2f(buf[k][2]) - mx) * inv;
            o0.w = expf(b2f(buf[k][3]) - mx) * inv;
            o1.x = expf(b2f(buf[k][4]) - mx) * inv;
            o1.y = expf(b2f(buf[k][5]) - mx) * inv;
            o1.z = expf(b2f(buf[k][6]) - mx) * inv;
            o1.w = expf(b2f(buf[k][7]) - mx) * inv;
            *(float4*)&dst[i * 8]     = o0;
            *(float4*)&dst[i * 8 + 4] = o1;
        }
    }
}

// ---------------------------------------------------------------------------
// in-place row softmax (fallback)
// ---------------------------------------------------------------------------
__global__ __launch_bounds__(256) void softmax_rows_kernel(float* __restrict__ logits, int N)
{
    const int b = blockIdx.x, t = threadIdx.x;
    __shared__ float red[256];
    float* row = logits + (size_t)b * N;

    float mx = -1e30f;
    for (int i = t; i < N; i += 256) mx = fmaxf(mx, row[i]);
    red[t] = mx; __syncthreads();
    for (int s = 128; s > 0; s >>= 1) { if (t < s) red[t] = fmaxf(red[t], red[t + s]); __syncthreads(); }
    mx = red[0]; __syncthreads();

    float sum = 0.f;
    for (int i = t; i < N; i += 256) sum += expf(row[i] - mx);
    red[t] = sum; __syncthreads();
    for (int s = 128; s > 0; s >>= 1) { if (t < s) red[t] += red[t + s]; __syncthreads(); }
    const float inv = 1.0f / red[0];
    __syncthreads();

    for (int i = t; i < N; i += 256) row[i] = expf(row[i] - mx) * inv;
}

// ---------------------------------------------------------------------------
extern "C" void kernel_launch(void* const* d_in, const int* in_sizes, int n_in,
                              void* d_out, int out_size, void* d_ws, size_t ws_size,
                              hipStream_t stream)
{
    const int*   tok    = (const int*)d_in[0];
    const float* hidden = (const float*)d_in[1];
    const float* enc    = (const float*)d_in[2];
    const float* emb    = (const float*)d_in[3];
    const float* attn_W = (const float*)d_in[4];
    const float* attn_b = (const float*)d_in[5];
    const float* comb_W = (const float*)d_in[6];
    const float* comb_b = (const float*)d_in[7];
    const float* W_ih   = (const float*)d_in[8];
    const float* W_hh   = (const float*)d_in[9];
    const float* b_ih   = (const float*)d_in[10];
    const float* b_hh   = (const float*)d_in[11];
    const float* out_W  = (const float*)d_in[12];
    const float* out_b  = (const float*)d_in[13];

    float* out   = (float*)d_out;
    float* pred  = out;                             // B*V
    float* hid_o = out + (size_t)B * V;             // NL*B*H
    float* attnw = hid_o + (size_t)NL * B * H;      // B*MAXLEN

    unsigned short* c2b    = (unsigned short*)pred;         // B*1024
    unsigned short* xb     = c2b  + (size_t)B * 1024;       // B*512
    unsigned short* h01b   = xb   + (size_t)B * 512;        // NL*B*512
    unsigned short* hn0b   = h01b + (size_t)NL * B * 512;   // B*512
    unsigned short* gi_b   = hn0b + (size_t)B * 512;        // B*1536
    unsigned short* gh_b   = gi_b + (size_t)B * 1536;       // B*1536
    unsigned short* Wihb   = gh_b + (size_t)B * 1536;       // 2*1536*512
    unsigned short* Whhb   = Wihb + (size_t)NL * 1536 * 512;
    unsigned short* combWb = Whhb + (size_t)NL * 1536 * 512; // 512*1024
    unsigned short* hn1b_fallback = combWb + (size_t)512 * 1024;

    const size_t outWb_e = (size_t)V * H;
    const size_t hn1b_e  = (size_t)B * H;
    const size_t bf_bytes = (outWb_e + hn1b_e) * sizeof(unsigned short);
    const bool lvl1 = ws_size >= bf_bytes;

    unsigned short* outWb = (unsigned short*)d_ws;
    unsigned short* hn1b  = lvl1 ? outWb + outWb_e : hn1b_fallback;

    unsigned short* h0b = h01b;
    unsigned short* h1b = h01b + (size_t)B * 512;

    // allow 128KB dynamic LDS for the 8-phase logits kernel (deterministic)
    (void)hipFuncSetAttribute((const void*)gemm_logits_8ph,
                              hipFuncAttributeMaxDynamicSharedMemorySize, 131072);

    // 1. fused embed + attention
    embed_attn_kernel<<<B, 256, 0, stream>>>(
        tok, emb, hidden, attn_W, attn_b, enc, attnw, c2b);

    // 2. batched conversions
    {
        const int e0 = 256, e1 = e0 + 768, e2 = e1 + 768, e3 = e2 + 2048;
        const int nblk = lvl1 ? e3 + 8000 : e3;
        batch_f2b_kernel<<<nblk, 256, 0, stream>>>(
            comb_W, combWb, e0,
            W_ih,   Wihb,   e1,
            W_hh,   Whhb,   e2,
            hidden, h01b,   e3,
            out_W,  outWb);
    }

    // 3. combine
    gemm_bf16_nt<1, 1, 0><<<dim3(512 / 128, B / 128), 256, 0, stream>>>(
        c2b, combWb, comb_b, xb, B, 512, 1024, 512, 0);

    // 4. GRU layer 0
    gemm_bf16_dual<<<dim3(1536 / 128, B / 128, 2), 256, 0, stream>>>(
        xb,  Wihb, b_ih, gi_b,
        h0b, Whhb, b_hh, gh_b, B, 1536, 512, 1536);
    gru_gates_kernel<<<(B * H / 8) / 256, 256, 0, stream>>>(
        gi_b, gh_b, hidden, hid_o, hn0b);

    // 5. GRU layer 1
    gemm_bf16_dual<<<dim3(1536 / 128, B / 128, 2), 256, 0, stream>>>(
        hn0b, Wihb + (size_t)1536 * 512, b_ih + 1536, gi_b,
        h1b,  Whhb + (size_t)1536 * 512, b_hh + 1536, gh_b, B, 1536, 512, 1536);
    gru_gates_kernel<<<(B * H / 8) / 256, 256, 0, stream>>>(
        gi_b, gh_b, hidden + (size_t)B * H, hid_o + (size_t)B * H, hn1b);

    // 6. logits (8-phase 256² kernel, fully unrolled) + softmax
    if (lvl1) {
        gemm_logits_8ph<<<dim3(B / 256, V / 256), 512, 131072, stream>>>(
            hn1b, outWb, out_b, pred);
        softmax_bf16_full_kernel<<<B, 512, 0, stream>>>(pred);
    } else {
        gemm_nt<0><<<dim3(V / 128, B / 128), 256, 0, stream>>>(
            hid_o + (size_t)B * H, out_W, out_b, pred, B, V, 512);
        softmax_rows_kernel<<<B, 256, 0, stream>>>(pred, V);
    }
}

// Round 15
// 762.405 us; speedup vs baseline: 4.1044x; 1.0149x over previous
//
#include <hip/hip_runtime.h>
#include <cstdint>
#include <cstddef>
#include <cmath>

#define B 4096
#define H 512
#define E 512
#define V 32000
#define NL 2
#define MAXLEN 99

typedef __attribute__((ext_vector_type(8))) short  bf16x8;
typedef __attribute__((ext_vector_type(4))) float  f32x4;
typedef __attribute__((ext_vector_type(8))) unsigned short ushort8;

__device__ __forceinline__ unsigned short f2b(float x) {
    union { float f; unsigned u; } c; c.f = x;
    unsigned r = c.u + 0x7fff + ((c.u >> 16) & 1);   // RNE to bf16
    return (unsigned short)(r >> 16);
}
__device__ __forceinline__ float b2f(unsigned short u) {
    return __uint_as_float((unsigned)u << 16);
}

#define GLOAD16(gp, lp)                                                        \
    __builtin_amdgcn_global_load_lds(                                          \
        (const __attribute__((address_space(1))) void*)(gp),                   \
        (__attribute__((address_space(3))) void*)(lp), 16, 0, 0)

// ---------------------------------------------------------------------------
// FUSED embed + attention (R12-proven)
// ---------------------------------------------------------------------------
__global__ __launch_bounds__(256) void embed_attn_kernel(
    const int* __restrict__ tok, const float* __restrict__ emb,
    const float* __restrict__ hidden0, const float* __restrict__ attn_W,
    const float* __restrict__ attn_b, const float* __restrict__ enc,
    float* __restrict__ attnw, unsigned short* __restrict__ c2b)
{
    const int b = blockIdx.x, t = threadIdx.x;
    __shared__ float qs[1024];
    __shared__ float ls[128];
    __shared__ float4 sm4[128];

    const int v = tok[b];
    const float2 e = ((const float2*)(emb + (size_t)v * E))[t];
    qs[2 * t] = e.x; qs[2 * t + 1] = e.y;
    ushort2 eb; eb.x = f2b(e.x); eb.y = f2b(e.y);
    *(ushort2*)&c2b[(size_t)b * 1024 + 2 * t] = eb;
    const float2 h = ((const float2*)(hidden0 + (size_t)b * H))[t];
    qs[512 + 2 * t] = h.x; qs[512 + 2 * t + 1] = h.y;
    __syncthreads();

    float s = -1e30f;
    if (t < MAXLEN) {
        const float4* w4 = (const float4*)(attn_W + (size_t)t * 1024);
        const float4* q4 = (const float4*)qs;
        float ax = 0.f, ay = 0.f, az = 0.f, aw = 0.f;
        #pragma unroll 8
        for (int k = 0; k < 256; ++k) {
            const float4 a = q4[k], w = w4[k];
            ax += a.x * w.x; ay += a.y * w.y; az += a.z * w.z; aw += a.w * w.w;
        }
        s = (ax + ay) + (az + aw) + attn_b[t];
    }
    if (t < 128) ls[t] = s;
    __syncthreads();

    float mx = -1e30f;
    for (int i = 0; i < 128; ++i) mx = fmaxf(mx, ls[i]);
    __syncthreads();

    float ex = 0.f;
    if (t < MAXLEN) ex = expf(s - mx);
    if (t < 128) ls[t] = ex;
    __syncthreads();

    float sum = 0.f;
    for (int i = 0; i < 128; ++i) sum += ls[i];
    const float inv = 1.0f / sum;

    if (t < MAXLEN) attnw[(size_t)b * MAXLEN + t] = ex * inv;

    const int half = t >> 7;
    const int cq   = t & 127;
    const float4* enc4 = (const float4*)(enc + (size_t)b * MAXLEN * H);
    float4 a4; a4.x = 0.f; a4.y = 0.f; a4.z = 0.f; a4.w = 0.f;
    for (int l = half; l < MAXLEN; l += 2) {
        const float wl = ls[l];
        const float4 ev = enc4[l * 128 + cq];
        a4.x += wl * ev.x; a4.y += wl * ev.y;
        a4.z += wl * ev.z; a4.w += wl * ev.w;
    }
    if (half == 0) sm4[cq] = a4;
    __syncthreads();
    if (half == 1) {
        const float4 p = sm4[cq];
        ushort4 ob;
        ob.x = f2b((p.x + a4.x) * inv);
        ob.y = f2b((p.y + a4.y) * inv);
        ob.z = f2b((p.z + a4.z) * inv);
        ob.w = f2b((p.w + a4.w) * inv);
        *(ushort4*)&c2b[(size_t)b * 1024 + 512 + 4 * cq] = ob;
    }
}

// ---------------------------------------------------------------------------
// batched fp32 -> bf16 conversion (R12-proven)
// ---------------------------------------------------------------------------
__global__ __launch_bounds__(256) void batch_f2b_kernel(
    const float* __restrict__ s0, unsigned short* __restrict__ d0, int e0,
    const float* __restrict__ s1, unsigned short* __restrict__ d1, int e1,
    const float* __restrict__ s2, unsigned short* __restrict__ d2, int e2,
    const float* __restrict__ s3, unsigned short* __restrict__ d3, int e3,
    const float* __restrict__ s4, unsigned short* __restrict__ d4)
{
    int blk = blockIdx.x;
    const float* s; unsigned short* d;
    if      (blk < e0) { s = s0; d = d0; }
    else if (blk < e1) { s = s1; d = d1; blk -= e0; }
    else if (blk < e2) { s = s2; d = d2; blk -= e1; }
    else if (blk < e3) { s = s3; d = d3; blk -= e2; }
    else               { s = s4; d = d4; blk -= e3; }
    const size_t i = ((size_t)blk * 256 + threadIdx.x) * 8;
    const float4 a = *(const float4*)(s + i);
    const float4 b = *(const float4*)(s + i + 4);
    ushort8 o;
    o[0] = f2b(a.x); o[1] = f2b(a.y); o[2] = f2b(a.z); o[3] = f2b(a.w);
    o[4] = f2b(b.x); o[5] = f2b(b.y); o[6] = f2b(b.z); o[7] = f2b(b.w);
    *(ushort8*)(d + i) = o;
}

// ---------------------------------------------------------------------------
// bf16 MFMA NT GEMM core (m97-class, 128² tile) — combine + GRU duals
// ---------------------------------------------------------------------------
template<int RELU, int OUTBF>
__device__ __forceinline__ void gemm_core(
    const unsigned short* __restrict__ A, const unsigned short* __restrict__ Wb,
    const float* __restrict__ bias, void* __restrict__ Cv,
    int M, int N, int K, int ldc, int colOff, int bm, int bn)
{
    __shared__ __align__(16) unsigned short As[2][4096];
    __shared__ __align__(16) unsigned short Bs[2][4096];

    const int tid  = threadIdx.x;
    const int lane = tid & 63;
    const int wid  = tid >> 6;
    const int wr   = (wid >> 1) * 64;
    const int wc   = (wid & 1) * 64;
    const int fr   = lane & 15;
    const int fk   = (lane >> 4) * 8;

    f32x4 acc[4][4];
    #pragma unroll
    for (int m = 0; m < 4; ++m)
        #pragma unroll
        for (int n = 0; n < 4; ++n) acc[m][n] = (f32x4)0.f;

    const int srow = tid >> 2;
    const int sk   = (tid & 3) * 8;

    const unsigned short* ga = A  + (size_t)(bm + srow) * K + sk;
    const unsigned short* gb = Wb + (size_t)(bn + srow) * K + sk;

    {
        GLOAD16(ga,                    &As[0][tid * 8]);
        GLOAD16(ga + (size_t)64 * K,   &As[0][2048 + tid * 8]);
        GLOAD16(gb,                    &Bs[0][tid * 8]);
        GLOAD16(gb + (size_t)64 * K,   &Bs[0][2048 + tid * 8]);
    }

    int buf = 0;
    for (int k0 = 0; k0 < K; k0 += 32) {
        __syncthreads();

        if (k0 + 32 < K) {
            const int nb = buf ^ 1;
            GLOAD16(ga + k0 + 32,                  &As[nb][tid * 8]);
            GLOAD16(ga + k0 + 32 + (size_t)64 * K, &As[nb][2048 + tid * 8]);
            GLOAD16(gb + k0 + 32,                  &Bs[nb][tid * 8]);
            GLOAD16(gb + k0 + 32 + (size_t)64 * K, &Bs[nb][2048 + tid * 8]);
        }

        bf16x8 af[4], bf_[4];
        #pragma unroll
        for (int m = 0; m < 4; ++m)
            af[m] = *(const bf16x8*)&As[buf][(wr + m * 16 + fr) * 32 + fk];
        #pragma unroll
        for (int n = 0; n < 4; ++n)
            bf_[n] = *(const bf16x8*)&Bs[buf][(wc + n * 16 + fr) * 32 + fk];

        #pragma unroll
        for (int m = 0; m < 4; ++m)
            #pragma unroll
            for (int n = 0; n < 4; ++n)
                acc[m][n] = __builtin_amdgcn_mfma_f32_16x16x32_bf16(
                    af[m], bf_[n], acc[m][n], 0, 0, 0);

        buf ^= 1;
    }

    float bv[4];
    #pragma unroll
    for (int n = 0; n < 4; ++n) bv[n] = bias[bn + wc + n * 16 + fr];

    if constexpr (OUTBF) {
        __syncthreads();
        unsigned short* smb = (wr == 0) ? (unsigned short*)As : (unsigned short*)Bs;
        #pragma unroll
        for (int m = 0; m < 4; ++m) {
            #pragma unroll
            for (int n = 0; n < 4; ++n) {
                #pragma unroll
                for (int r = 0; r < 4; ++r) {
                    float v = acc[m][n][r] + bv[n];
                    if (RELU) v = fmaxf(v, 0.f);
                    const int row  = m * 16 + (lane >> 4) * 4 + r;
                    const int col  = wc + n * 16 + fr;
                    const int cc   = col ^ ((row & 12) << 3);
                    smb[row * 128 + cc] = f2b(v);
                }
            }
        }
        __syncthreads();
        unsigned short* Cb = (unsigned short*)Cv;
        const int rrow = tid >> 4;
        const int cch  = (tid & 15) * 8;
        #pragma unroll
        for (int p = 0; p < 8; ++p) {
            const int row  = p * 16 + rrow;
            const int lrow = row & 63;
            unsigned short* smr = (p < 4) ? (unsigned short*)As : (unsigned short*)Bs;
            const int cc = cch ^ ((row & 12) << 3);
            const ushort8 v = *(const ushort8*)&smr[lrow * 128 + cc];
            *(ushort8*)&Cb[(size_t)(bm + row) * ldc + colOff + bn + cch] = v;
        }
    } else {
        float* Cf = (float*)Cv;
        #pragma unroll
        for (int m = 0; m < 4; ++m) {
            #pragma unroll
            for (int n = 0; n < 4; ++n) {
                const int col = bn + wc + n * 16 + fr;
                const int row = bm + wr + m * 16 + (lane >> 4) * 4;
                #pragma unroll
                for (int r = 0; r < 4; ++r) {
                    float v = acc[m][n][r] + bv[n];
                    if (RELU) v = fmaxf(v, 0.f);
                    Cf[(size_t)(row + r) * ldc + colOff + col] = v;
                }
            }
        }
    }
}

template<int RELU, int OUTBF, int GSWAP>
__global__ __launch_bounds__(256) void gemm_bf16_nt(
    const unsigned short* __restrict__ A, const unsigned short* __restrict__ Wb,
    const float* __restrict__ bias, void* __restrict__ Cv,
    int M, int N, int K, int ldc, int colOff)
{
    const int bn = (GSWAP ? blockIdx.y : blockIdx.x) * 128;
    const int bm = (GSWAP ? blockIdx.x : blockIdx.y) * 128;
    gemm_core<RELU, OUTBF>(A, Wb, bias, Cv, M, N, K, ldc, colOff, bm, bn);
}

__global__ __launch_bounds__(256) void gemm_bf16_dual(
    const unsigned short* __restrict__ A0, const unsigned short* __restrict__ W0,
    const float* __restrict__ b0, void* __restrict__ C0,
    const unsigned short* __restrict__ A1, const unsigned short* __restrict__ W1,
    const float* __restrict__ b1, void* __restrict__ C1,
    int M, int N, int K, int ldc)
{
    const int bn = blockIdx.x * 128;
    const int bm = blockIdx.y * 128;
    const unsigned short* A = blockIdx.z ? A1 : A0;
    const unsigned short* W = blockIdx.z ? W1 : W0;
    const float* bias       = blockIdx.z ? b1 : b0;
    void* C                 = blockIdx.z ? C1 : C0;
    gemm_core<0, 1>(A, W, bias, C, M, N, K, ldc, 0, bm, bn);
}

// ---------------------------------------------------------------------------
// LOGITS GEMM — 256x256, BK=64, 8 waves, 8-phase pipeline, FULLY UNROLLED,
// now with T2 XOR-swizzle (both-sides: pre-swizzled global source + swizzled
// ds_read). LDS: [buf(2)][op(2)] regions of 32KB, each [256 rows][64 k]
// (128B rows, 8 granules of 16B). Read granule g at row r lives at g^(r&7);
// the staging fetches global granule gl^(r&7) into linear chunk gl.
// R14 layout had 64B rows -> 8-way bank conflict (SQ_LDS_BANK_CONFLICT
// 1.64e7); this layout reduces to the free 2-way.
// ---------------------------------------------------------------------------
__global__ __launch_bounds__(512, 2) void gemm_logits_8ph(
    const unsigned short* __restrict__ A, const unsigned short* __restrict__ Wb,
    const float* __restrict__ bias, float* __restrict__ Cv)
{
    extern __shared__ unsigned short AB[];          // 65536 ushorts = 128 KB
    const int tid  = threadIdx.x;
    const int lane = tid & 63;
    const int wid  = tid >> 6;                      // 0..7
    const int wr   = wid >> 2;                      // 0..1  (M)
    const int wc   = wid & 3;                       // 0..3  (N)
    const int fr   = lane & 15;
    const int gq   = lane >> 4;                     // k-granule quarter 0..3
    const int bm   = blockIdx.x * 256;
    const int bn   = blockIdx.y * 256;

    constexpr int NT = 512 / 64;                    // 8 K-tiles
    constexpr int NH = 4 * NT;                      // 32 halves

    f32x4 acc[8][4];
    #pragma unroll
    for (int m = 0; m < 8; ++m)
        #pragma unroll
        for (int n = 0; n < 4; ++n) acc[m][n] = (f32x4)0.f;

    // half h: th=h>>2, hh=h&3: op=hh&1 (0=A,1=B), rhalf=hh>>1 (rows 0-127/128-255)
    auto STAGE = [&](int h) {
        const int th = h >> 2, hh = h & 3;
        const int op = hh & 1, rh = hh >> 1;
        const unsigned short* src = op ? Wb : A;
        const int rbase = (op ? bn : bm) + rh * 128;
        const int kbase = th * 64;
        unsigned short* dst = AB + ((size_t)((th & 1) * 2 + op)) * 16384 + rh * 8192;
        #pragma unroll
        for (int j = 0; j < 2; ++j) {
            const int c  = tid + j * 512;           // 0..1023
            const int lr = c >> 3;                  // local row 0..127
            const int gl = c & 7;                   // linear LDS granule
            GLOAD16(src + (size_t)(rbase + lr) * 512 + kbase + ((gl ^ (lr & 7)) * 8),
                    &dst[c * 8]);
        }
    };

    // prologue: halves 0..6 (tile0 complete + 3 halves of tile1 in flight)
    #pragma unroll
    for (int h = 0; h < 7; ++h) STAGE(h);

    bf16x8 af[8];
    #pragma unroll
    for (int t = 0; t < NT; ++t) {                  // COMPILE-TIME tiles
        #pragma unroll
        for (int sub = 0; sub < 4; ++sub) {         // COMPILE-TIME sub-phases
            const int g  = t * 4 + sub;
            const int a  = sub >> 1;                // k-half (const)
            const int np = sub & 1;                 // n-pair (const)

            if (sub == 0) {
                if (t == NT - 1) asm volatile("s_waitcnt vmcnt(0)" ::: "memory");
                else             asm volatile("s_waitcnt vmcnt(6)" ::: "memory");
                __builtin_amdgcn_s_barrier();       // tile t staged + visible
            }
            if (g + 7 < NH) STAGE(g + 7);

            const unsigned short* Ar = AB + ((size_t)((t & 1) * 2 + 0)) * 16384;
            const unsigned short* Br = AB + ((size_t)((t & 1) * 2 + 1)) * 16384;
            const int gk = a * 4 + gq;              // k-granule 0..7

            if (np == 0) {
                #pragma unroll
                for (int m = 0; m < 8; ++m) {
                    const int rA = wr * 128 + m * 16 + fr;
                    af[m] = *(const bf16x8*)&Ar[rA * 64 + ((gk ^ (rA & 7)) * 8)];
                }
            }
            const int rB0 = wc * 64 + np * 32 + fr;
            const int rB1 = rB0 + 16;
            const bf16x8 bf0 = *(const bf16x8*)&Br[rB0 * 64 + ((gk ^ (rB0 & 7)) * 8)];
            const bf16x8 bf1 = *(const bf16x8*)&Br[rB1 * 64 + ((gk ^ (rB1 & 7)) * 8)];

            __builtin_amdgcn_s_setprio(1);
            #pragma unroll
            for (int m = 0; m < 8; ++m) {
                acc[m][np * 2 + 0] = __builtin_amdgcn_mfma_f32_16x16x32_bf16(
                    af[m], bf0, acc[m][np * 2 + 0], 0, 0, 0);
                acc[m][np * 2 + 1] = __builtin_amdgcn_mfma_f32_16x16x32_bf16(
                    af[m], bf1, acc[m][np * 2 + 1], 0, 0, 0);
            }
            __builtin_amdgcn_s_setprio(0);
            __builtin_amdgcn_s_barrier();           // reads of this phase done
        }
    }

    // epilogue: per-wave private 16KB LDS region -> dense ushort8 stores
    float bv[4];
    #pragma unroll
    for (int n = 0; n < 4; ++n) bv[n] = bias[bn + wc * 64 + n * 16 + fr];

    unsigned short* reg = AB + (size_t)wid * 8192;
    #pragma unroll
    for (int m = 0; m < 8; ++m) {
        #pragma unroll
        for (int n = 0; n < 4; ++n) {
            #pragma unroll
            for (int r = 0; r < 4; ++r) {
                const int row = m * 16 + (lane >> 4) * 4 + r;   // 0..127
                const int col = n * 16 + fr;                    // 0..63
                reg[row * 64 + col] = f2b(acc[m][n][r] + bv[n]);
            }
        }
    }
    unsigned short* Cb = (unsigned short*)Cv;
    const int cch = (lane & 7) * 8;
    const int r0  = lane >> 3;
    #pragma unroll
    for (int p = 0; p < 16; ++p) {
        const int row = r0 + p * 8;                 // 0..127
        const ushort8 v = *(const ushort8*)&reg[row * 64 + cch];
        *(ushort8*)&Cb[(size_t)(bm + wr * 128 + row) * (2 * V) + V + bn + wc * 64 + cch] = v;
    }
}

// ---------------------------------------------------------------------------
// fp32 NT GEMM (fallback for logits if ws too small)
// ---------------------------------------------------------------------------
template<int RELU>
__global__ __launch_bounds__(256) void gemm_nt(
    const float* __restrict__ A, const float* __restrict__ W,
    const float* __restrict__ bias, float* __restrict__ C,
    int M, int N, int K)
{
    constexpr int BM = 128, BN = 128, BK = 32;
    __shared__ float As[BK][BM + 4];
    __shared__ float Bs[BK][BN + 4];

    const int tid = threadIdx.x;
    const int bn = blockIdx.x * BN;
    const int bm = blockIdx.y * BM;
    const int tx = tid & 15;
    const int ty = tid >> 4;

    float acc[8][8];
    #pragma unroll
    for (int i = 0; i < 8; ++i)
        #pragma unroll
        for (int j = 0; j < 8; ++j) acc[i][j] = 0.f;

    const int lkv = tid & 7;
    const int lm0 = tid >> 3;

    for (int k0 = 0; k0 < K; k0 += BK) {
        #pragma unroll
        for (int r = 0; r < 4; ++r) {
            const int m = lm0 + 32 * r;
            const float4 va = *(const float4*)(A + (size_t)(bm + m) * K + k0 + lkv * 4);
            As[lkv * 4 + 0][m] = va.x; As[lkv * 4 + 1][m] = va.y;
            As[lkv * 4 + 2][m] = va.z; As[lkv * 4 + 3][m] = va.w;
            const float4 vb = *(const float4*)(W + (size_t)(bn + m) * K + k0 + lkv * 4);
            Bs[lkv * 4 + 0][m] = vb.x; Bs[lkv * 4 + 1][m] = vb.y;
            Bs[lkv * 4 + 2][m] = vb.z; Bs[lkv * 4 + 3][m] = vb.w;
        }
        __syncthreads();

        #pragma unroll
        for (int kk = 0; kk < BK; ++kk) {
            float a[8], bb[8];
            *(float4*)&a[0]  = *(const float4*)&As[kk][ty * 8];
            *(float4*)&a[4]  = *(const float4*)&As[kk][ty * 8 + 4];
            *(float4*)&bb[0] = *(const float4*)&Bs[kk][tx * 8];
            *(float4*)&bb[4] = *(const float4*)&Bs[kk][tx * 8 + 4];
            #pragma unroll
            for (int i = 0; i < 8; ++i)
                #pragma unroll
                for (int j = 0; j < 8; ++j) acc[i][j] += a[i] * bb[j];
        }
        __syncthreads();
    }

    #pragma unroll
    for (int i = 0; i < 8; ++i) {
        const int row = bm + ty * 8 + i;
        float* crow = C + (size_t)row * N + bn + tx * 8;
        #pragma unroll
        for (int j = 0; j < 8; ++j) {
            float v = acc[i][j] + bias[bn + tx * 8 + j];
            if (RELU) v = fmaxf(v, 0.f);
            crow[j] = v;
        }
    }
}

// ---------------------------------------------------------------------------
// GRU gates (vectorized x8)
// ---------------------------------------------------------------------------
__global__ __launch_bounds__(256) void gru_gates_kernel(
    const unsigned short* __restrict__ gi, const unsigned short* __restrict__ gh,
    const float* __restrict__ h, float* __restrict__ hnew,
    unsigned short* __restrict__ hnew_b)
{
    const int idx = blockIdx.x * 256 + threadIdx.x;
    const int b  = idx >> 6;
    const int j8 = (idx & 63) * 8;
    const size_t base = (size_t)b * 1536;
    const ushort8 vir = *(const ushort8*)&gi[base + j8];
    const ushort8 viz = *(const ushort8*)&gi[base + 512 + j8];
    const ushort8 vin = *(const ushort8*)&gi[base + 1024 + j8];
    const ushort8 vhr = *(const ushort8*)&gh[base + j8];
    const ushort8 vhz = *(const ushort8*)&gh[base + 512 + j8];
    const ushort8 vhn = *(const ushort8*)&gh[base + 1024 + j8];
    const size_t hi = (size_t)b * 512 + j8;
    const float4 h0 = *(const float4*)&h[hi];
    const float4 h1 = *(const float4*)&h[hi + 4];
    const float hval[8] = {h0.x, h0.y, h0.z, h0.w, h1.x, h1.y, h1.z, h1.w};
    float hv[8];
    ushort8 ob;
    #pragma unroll
    for (int k = 0; k < 8; ++k) {
        const float r = 1.f / (1.f + expf(-(b2f(vir[k]) + b2f(vhr[k]))));
        const float z = 1.f / (1.f + expf(-(b2f(viz[k]) + b2f(vhz[k]))));
        const float n = tanhf(b2f(vin[k]) + r * b2f(vhn[k]));
        hv[k] = (1.f - z) * n + z * hval[k];
        ob[k] = f2b(hv[k]);
    }
    float4 o0, o1;
    o0.x = hv[0]; o0.y = hv[1]; o0.z = hv[2]; o0.w = hv[3];
    o1.x = hv[4]; o1.y = hv[5]; o1.z = hv[6]; o1.w = hv[7];
    *(float4*)&hnew[hi]     = o0;
    *(float4*)&hnew[hi + 4] = o1;
    *(ushort8*)&hnew_b[hi]  = ob;
}

// ---------------------------------------------------------------------------
// FULL softmax from bf16 logits (R12-proven, 512 thr)
// ---------------------------------------------------------------------------
__global__ __launch_bounds__(512) void softmax_bf16_full_kernel(float* logits)
{
    const int row = blockIdx.x, t = threadIdx.x;
    __shared__ float red[512];

    const unsigned short* src = (const unsigned short*)logits + (size_t)row * (2 * V) + V;
    ushort8 buf[8];
    #pragma unroll
    for (int k = 0; k < 8; ++k) {
        const int i = t + 512 * k;
        if (i < V / 8) buf[k] = *(const ushort8*)&src[i * 8];
    }

    float mx = -1e30f;
    #pragma unroll
    for (int k = 0; k < 8; ++k) {
        const int i = t + 512 * k;
        if (i < V / 8) {
            #pragma unroll
            for (int j = 0; j < 8; ++j) mx = fmaxf(mx, b2f(buf[k][j]));
        }
    }
    red[t] = mx; __syncthreads();
    for (int s = 256; s > 0; s >>= 1) {
        if (t < s) red[t] = fmaxf(red[t], red[t + s]);
        __syncthreads();
    }
    mx = red[0]; __syncthreads();

    float sum = 0.f;
    #pragma unroll
    for (int k = 0; k < 8; ++k) {
        const int i = t + 512 * k;
        if (i < V / 8) {
            #pragma unroll
            for (int j = 0; j < 8; ++j) sum += expf(b2f(buf[k][j]) - mx);
        }
    }
    red[t] = sum; __syncthreads();
    for (int s = 256; s > 0; s >>= 1) {
        if (t < s) red[t] += red[t + s];
        __syncthreads();
    }
    const float inv = 1.f / red[0];

    float* dst = logits + (size_t)row * V;
    #pragma unroll
    for (int k = 0; k < 8; ++k) {
        const int i = t + 512 * k;
        if (i < V / 8) {
            float4 o0, o1;
            o0.x = expf(b2f(buf[k][0]) - mx) * inv;
            o0.y = expf(b2f(buf[k][1]) - mx) * inv;
            o0.z = expf(b2f(buf[k][2]) - mx) * inv;
            o0.w = expf(b2f(buf[k][3]) - mx) * inv;
            o1.x = expf(b2f(buf[k][4]) - mx) * inv;
            o1.y = expf(b2f(buf[k][5]) - mx) * inv;
            o1.z = expf(b2f(buf[k][6]) - mx) * inv;
            o1.w = expf(b2f(buf[k][7]) - mx) * inv;
            *(float4*)&dst[i * 8]     = o0;
            *(float4*)&dst[i * 8 + 4] = o1;
        }
    }
}

// ---------------------------------------------------------------------------
// in-place row softmax (fallback)
// ---------------------------------------------------------------------------
__global__ __launch_bounds__(256) void softmax_rows_kernel(float* __restrict__ logits, int N)
{
    const int b = blockIdx.x, t = threadIdx.x;
    __shared__ float red[256];
    float* row = logits + (size_t)b * N;

    float mx = -1e30f;
    for (int i = t; i < N; i += 256) mx = fmaxf(mx, row[i]);
    red[t] = mx; __syncthreads();
    for (int s = 128; s > 0; s >>= 1) { if (t < s) red[t] = fmaxf(red[t], red[t + s]); __syncthreads(); }
    mx = red[0]; __syncthreads();

    float sum = 0.f;
    for (int i = t; i < N; i += 256) sum += expf(row[i] - mx);
    red[t] = sum; __syncthreads();
    for (int s = 128; s > 0; s >>= 1) { if (t < s) red[t] += red[t + s]; __syncthreads(); }
    const float inv = 1.0f / red[0];
    __syncthreads();

    for (int i = t; i < N; i += 256) row[i] = expf(row[i] - mx) * inv;
}

// ---------------------------------------------------------------------------
extern "C" void kernel_launch(void* const* d_in, const int* in_sizes, int n_in,
                              void* d_out, int out_size, void* d_ws, size_t ws_size,
                              hipStream_t stream)
{
    const int*   tok    = (const int*)d_in[0];
    const float* hidden = (const float*)d_in[1];
    const float* enc    = (const float*)d_in[2];
    const float* emb    = (const float*)d_in[3];
    const float* attn_W = (const float*)d_in[4];
    const float* attn_b = (const float*)d_in[5];
    const float* comb_W = (const float*)d_in[6];
    const float* comb_b = (const float*)d_in[7];
    const float* W_ih   = (const float*)d_in[8];
    const float* W_hh   = (const float*)d_in[9];
    const float* b_ih   = (const float*)d_in[10];
    const float* b_hh   = (const float*)d_in[11];
    const float* out_W  = (const float*)d_in[12];
    const float* out_b  = (const float*)d_in[13];

    float* out   = (float*)d_out;
    float* pred  = out;                             // B*V
    float* hid_o = out + (size_t)B * V;             // NL*B*H
    float* attnw = hid_o + (size_t)NL * B * H;      // B*MAXLEN

    unsigned short* c2b    = (unsigned short*)pred;         // B*1024
    unsigned short* xb     = c2b  + (size_t)B * 1024;       // B*512
    unsigned short* h01b   = xb   + (size_t)B * 512;        // NL*B*512
    unsigned short* hn0b   = h01b + (size_t)NL * B * 512;   // B*512
    unsigned short* gi_b   = hn0b + (size_t)B * 512;        // B*1536
    unsigned short* gh_b   = gi_b + (size_t)B * 1536;       // B*1536
    unsigned short* Wihb   = gh_b + (size_t)B * 1536;       // 2*1536*512
    unsigned short* Whhb   = Wihb + (size_t)NL * 1536 * 512;
    unsigned short* combWb = Whhb + (size_t)NL * 1536 * 512; // 512*1024
    unsigned short* hn1b_fallback = combWb + (size_t)512 * 1024;

    const size_t outWb_e = (size_t)V * H;
    const size_t hn1b_e  = (size_t)B * H;
    const size_t bf_bytes = (outWb_e + hn1b_e) * sizeof(unsigned short);
    const bool lvl1 = ws_size >= bf_bytes;

    unsigned short* outWb = (unsigned short*)d_ws;
    unsigned short* hn1b  = lvl1 ? outWb + outWb_e : hn1b_fallback;

    unsigned short* h0b = h01b;
    unsigned short* h1b = h01b + (size_t)B * 512;

    // allow 128KB dynamic LDS for the 8-phase logits kernel (deterministic)
    (void)hipFuncSetAttribute((const void*)gemm_logits_8ph,
                              hipFuncAttributeMaxDynamicSharedMemorySize, 131072);

    // 1. fused embed + attention
    embed_attn_kernel<<<B, 256, 0, stream>>>(
        tok, emb, hidden, attn_W, attn_b, enc, attnw, c2b);

    // 2. batched conversions
    {
        const int e0 = 256, e1 = e0 + 768, e2 = e1 + 768, e3 = e2 + 2048;
        const int nblk = lvl1 ? e3 + 8000 : e3;
        batch_f2b_kernel<<<nblk, 256, 0, stream>>>(
            comb_W, combWb, e0,
            W_ih,   Wihb,   e1,
            W_hh,   Whhb,   e2,
            hidden, h01b,   e3,
            out_W,  outWb);
    }

    // 3. combine
    gemm_bf16_nt<1, 1, 0><<<dim3(512 / 128, B / 128), 256, 0, stream>>>(
        c2b, combWb, comb_b, xb, B, 512, 1024, 512, 0);

    // 4. GRU layer 0
    gemm_bf16_dual<<<dim3(1536 / 128, B / 128, 2), 256, 0, stream>>>(
        xb,  Wihb, b_ih, gi_b,
        h0b, Whhb, b_hh, gh_b, B, 1536, 512, 1536);
    gru_gates_kernel<<<(B * H / 8) / 256, 256, 0, stream>>>(
        gi_b, gh_b, hidden, hid_o, hn0b);

    // 5. GRU layer 1
    gemm_bf16_dual<<<dim3(1536 / 128, B / 128, 2), 256, 0, stream>>>(
        hn0b, Wihb + (size_t)1536 * 512, b_ih + 1536, gi_b,
        h1b,  Whhb + (size_t)1536 * 512, b_hh + 1536, gh_b, B, 1536, 512, 1536);
    gru_gates_kernel<<<(B * H / 8) / 256, 256, 0, stream>>>(
        gi_b, gh_b, hidden + (size_t)B * H, hid_o + (size_t)B * H, hn1b);

    // 6. logits (8-phase 256², T2-swizzled) + softmax
    if (lvl1) {
        gemm_logits_8ph<<<dim3(B / 256, V / 256), 512, 131072, stream>>>(
            hn1b, outWb, out_b, pred);
        softmax_bf16_full_kernel<<<B, 512, 0, stream>>>(pred);
    } else {
        gemm_nt<0><<<dim3(V / 128, B / 128), 256, 0, stream>>>(
            hid_o + (size_t)B * H, out_W, out_b, pred, B, V, 512);
        softmax_rows_kernel<<<B, 256, 0, stream>>>(pred, V);
    }
}